// Round 1
// baseline (113.607 us; speedup 1.0000x reference)
//
#include <hip/hip_runtime.h>
#include <math.h>

// OscillatorEngine on MI355X.
// N=8192 cells, D_IN=512, D_H=1024, 8 factions of 1024, dc=256, SYNC=.15, DEBATE=.15
//
// Algebraic restructuring (exact in real arithmetic):
//  interactions[i] = (K/N) * (sin p_i * Sc_i - cos p_i * Ss_i),
//     Sc_i = sum_j sigmoid(C[i][j]) cos p_j,  Ss_i = sum_j sigmoid(C[i][j]) sin p_j
//  cell_hiddens[i][d] = a_i*w0[d] + b_i*w1[d] + bp[d]   (rank-2 in per-cell scalars)
//     a_i = .85 sn_i + .15 S_f  (+debate blend with global mean sbar),  same for b_i
//  pre1[i][h] = a_i*u0[h] + b_i*u1[h] + u2[h],
//     u0 = w0 @ W1a, u1 = w1 @ W1a, u2 = bp @ W1a + x @ W1b + b_enc1
//  weighted = (sum_i w_i tanh(pre1[i])) @ w_enc2 + b_enc2   (since sum_i w_i = 1)
//  output   = weighted @ w_out + b_out

#define NC   8192
#define DH   1024
#define DIN  512

// workspace layout (float offsets)
constexpr int IMG = 0, SBAR = 1, CBAR = 2, MPC = 3, MPS = 4, DEN = 5, TENS = 6;
constexpr int SFO = 8, CFO = 16;                 // faction means [8] each
constexpr int SN0 = 32;                          // sin(old phases) [8192]
constexpr int CN0 = SN0 + NC;                    // cos(old phases)
constexpr int SNN = CN0 + NC;                    // sin(new phases)
constexpr int CNN = SNN + NC;                    // cos(new phases)
constexpr int UPART  = CNN + NC;                 // [16][3][1024]
constexpr int UFIN   = UPART + 16 * 3 * DH;      // [3][1024]
constexpr int TPART  = UFIN + 3 * DH;            // [128][1024]
constexpr int W2PART = TPART + 128 * DH;         // [16][1024]
constexpr int OPART  = W2PART + 16 * DH;         // [16][512]
// total = OPART + 16*512 = 240672 floats (~0.94 MB)

__device__ __forceinline__ float frcp(float x) { return __builtin_amdgcn_rcpf(x); }
__device__ __forceinline__ float sigm(float x) { return frcp(1.f + __expf(-x)); }
__device__ __forceinline__ float ftanh(float x) { return 1.f - 2.f * frcp(__expf(2.f * x) + 1.f); }

template <int BS>
__device__ __forceinline__ float block_reduce(float v, float* sh) {
  #pragma unroll
  for (int m = 1; m < 64; m <<= 1) v += __shfl_xor(v, m, 64);
  constexpr int NW = BS / 64;
  int lane = threadIdx.x & 63, w = threadIdx.x >> 6;
  if (lane == 0) sh[w] = v;
  __syncthreads();
  if (w == 0) {
    float x = (lane < NW) ? sh[lane] : 0.f;
    #pragma unroll
    for (int m = 1; m < NW; m <<= 1) x += __shfl_xor(x, m, 64);
    if (lane == 0) sh[0] = x;
  }
  __syncthreads();
  float r = sh[0];
  __syncthreads();
  return r;
}

// K1: sin/cos of old phases; block 32 computes ||x||
__global__ __launch_bounds__(256) void k_prep(const float* __restrict__ phases,
                                              const float* __restrict__ x,
                                              float* __restrict__ W) {
  __shared__ float sh[4];
  int b = blockIdx.x, t = threadIdx.x;
  if (b < 32) {
    int i = b * 256 + t;
    float s, c;
    sincosf(phases[i], &s, &c);
    W[SN0 + i] = s;
    W[CN0 + i] = c;
  } else {
    float v = 0.f;
    float x0 = x[t], x1 = x[t + 256];
    v = x0 * x0 + x1 * x1;
    v = block_reduce<256>(v, sh);
    if (t == 0) W[IMG] = sqrtf(v);
  }
}

// K2: the 256 MB streaming pass. One block per row of coupling.
__global__ __launch_bounds__(256) void k_rows(const float* __restrict__ coupling,
                                              const float* __restrict__ phases,
                                              const float* __restrict__ omegas,
                                              const float* __restrict__ Kp,
                                              float* __restrict__ W) {
  __shared__ float sh[4];
  int row = blockIdx.x, t = threadIdx.x;
  const float4* crow = (const float4*)(coupling + (size_t)row * NC);
  const float4* s4 = (const float4*)(W + SN0);
  const float4* c4 = (const float4*)(W + CN0);
  float sc = 0.f, ss = 0.f;
  #pragma unroll
  for (int k = 0; k < 8; ++k) {
    int idx = k * 256 + t;
    float4 v = crow[idx];
    float4 cc = c4[idx];
    float4 sv = s4[idx];
    float g;
    g = sigm(v.x); sc = fmaf(g, cc.x, sc); ss = fmaf(g, sv.x, ss);
    g = sigm(v.y); sc = fmaf(g, cc.y, sc); ss = fmaf(g, sv.y, ss);
    g = sigm(v.z); sc = fmaf(g, cc.z, sc); ss = fmaf(g, sv.z, ss);
    g = sigm(v.w); sc = fmaf(g, cc.w, sc); ss = fmaf(g, sv.w, ss);
  }
  sc = block_reduce<256>(sc, sh);
  ss = block_reduce<256>(ss, sh);
  if (t == 0) {
    float kk = Kp[0];
    float si = W[SN0 + row], ci = W[CN0 + row];
    float inter = (kk / (float)NC) * (si * sc - ci * ss);
    float dtheta = omegas[row] + inter + 0.1f * W[IMG];
    float pn = phases[row] + 0.1f * dtheta;  // mod 2pi dropped: only sin/cos consumed
    float s, c;
    sincosf(pn, &s, &c);
    W[SNN + row] = s;
    W[CNN + row] = c;
  }
}

// K3: faction means, global means, tension, mean_phase, softmax denom. One block.
__global__ __launch_bounds__(1024) void k_stats(float* __restrict__ W) {
  __shared__ float sh[16];
  int t = threadIdx.x;
  float ssum = 0.f, csum = 0.f;
  #pragma unroll
  for (int f = 0; f < 8; ++f) {
    float S = block_reduce<1024>(W[SNN + f * 1024 + t], sh);
    float C = block_reduce<1024>(W[CNN + f * 1024 + t], sh);
    if (t == 0) {
      W[SFO + f] = S * (1.f / 1024.f);
      W[CFO + f] = C * (1.f / 1024.f);
    }
    ssum += S;
    csum += C;
  }
  float sbar = ssum * (1.f / (float)NC);
  float cbar = csum * (1.f / (float)NC);
  float mp = atan2f(sbar, cbar);
  float mpc = cosf(mp), mps = sinf(mp);
  if (t == 0) {
    W[SBAR] = sbar;
    W[CBAR] = cbar;
    W[MPC] = mpc;
    W[MPS] = mps;
    float r = sqrtf(cbar * cbar + sbar * sbar);
    W[TENS] = fabsf(r - 0.5f) * 2.f;
  }
  float dsum = 0.f;
  #pragma unroll
  for (int f = 0; f < 8; ++f) {
    int i = f * 1024 + t;
    float coh = W[CNN + i] * mpc + W[SNN + i] * mps;
    dsum += __expf(5.f * coh - 5.f);  // shift by const 5: cancels in normalization
  }
  float D = block_reduce<1024>(dsum, sh);
  if (t == 0) W[DEN] = D;
}

// K4: u0/u1/u2 partials. grid (4 h-groups, 16 d-chunks)
__global__ __launch_bounds__(256) void k_uprep(const float* __restrict__ w_p2h,
                                               const float* __restrict__ b_p2h,
                                               const float* __restrict__ w_enc1,
                                               const float* __restrict__ b_enc1,
                                               const float* __restrict__ x,
                                               float* __restrict__ W) {
  int h = blockIdx.x * 256 + threadIdx.x;
  int dy = blockIdx.y;
  float a0 = 0.f, a1 = 0.f, a2 = 0.f;
  for (int d = dy * 64; d < dy * 64 + 64; ++d) {
    float r = w_enc1[d * DH + h];
    a0 = fmaf(w_p2h[d], r, a0);
    a1 = fmaf(w_p2h[DH + d], r, a1);
    a2 = fmaf(b_p2h[d], r, a2);
  }
  for (int k = dy * 32; k < dy * 32 + 32; ++k)
    a2 = fmaf(x[k], w_enc1[(DH + k) * DH + h], a2);
  if (dy == 0) a2 += b_enc1[h];
  float* up = W + UPART + dy * 3 * DH;
  up[h] = a0;
  up[DH + h] = a1;
  up[2 * DH + h] = a2;
}

// K5: reduce the 16 u-partials
__global__ __launch_bounds__(256) void k_ured(float* __restrict__ W) {
  int j = blockIdx.x * 256 + threadIdx.x;  // j < 3072
  float v = 0.f;
  #pragma unroll
  for (int p = 0; p < 16; ++p) v += W[UPART + p * 3 * DH + j];
  W[UFIN + j] = v;
}

// K6: per-cell rank-2 eval + tanh + softmax-weighted accumulate. 128 blocks x 64 cells.
__global__ __launch_bounds__(256) void k_cells(const int* __restrict__ step,
                                               float* __restrict__ W) {
  int t = threadIdx.x, b = blockIdx.x;
  float u0[4], u1[4], u2[4], acc[4] = {0.f, 0.f, 0.f, 0.f};
  #pragma unroll
  for (int k = 0; k < 4; ++k) {
    int h = t + k * 256;
    u0[k] = W[UFIN + h];
    u1[k] = W[UFIN + DH + h];
    u2[k] = W[UFIN + 2 * DH + h];
  }
  bool debate = step[0] > 5;
  float sbar = W[SBAR], cbar = W[CBAR], mpc = W[MPC], mps = W[MPS];
  float invden = 1.0f / W[DEN];
  int i0 = b * 64;
  int f = i0 >> 10;  // 64-cell chunk never crosses a faction boundary
  float Sf = W[SFO + f], Cf = W[CFO + f];
  bool deb = debate && ((i0 & 1023) < 256);  // dc = FS/4 = 256; uniform per chunk
  for (int j = 0; j < 64; ++j) {
    int i = i0 + j;
    float s = W[SNN + i], c = W[CNN + i];
    float a = fmaf(0.15f, Sf, 0.85f * s);
    float bb = fmaf(0.15f, Cf, 0.85f * c);
    if (deb) {
      a = fmaf(0.15f, sbar, 0.85f * a);
      bb = fmaf(0.15f, cbar, 0.85f * bb);
    }
    float coh = c * mpc + s * mps;
    float w = __expf(5.f * coh - 5.f) * invden;
    #pragma unroll
    for (int k = 0; k < 4; ++k) {
      float pre = fmaf(a, u0[k], fmaf(bb, u1[k], u2[k]));
      acc[k] = fmaf(w, ftanh(pre), acc[k]);
    }
  }
  #pragma unroll
  for (int k = 0; k < 4; ++k) W[TPART + b * DH + t + k * 256] = acc[k];
}

// K7: t_sum chunk reduce + matvec with w_enc2. grid (4 c-groups, 16 h-chunks)
__global__ __launch_bounds__(256) void k_wv(const float* __restrict__ w_enc2,
                                            const float* __restrict__ b_enc2,
                                            float* __restrict__ W) {
  __shared__ float ts[64];
  int t = threadIdx.x, cb = blockIdx.x, hb = blockIdx.y;
  if (t < 64) {
    int h = hb * 64 + t;
    float v = 0.f;
    for (int p = 0; p < 128; ++p) v += W[TPART + p * DH + h];
    ts[t] = v;
  }
  __syncthreads();
  int c = cb * 256 + t;
  float acc = (hb == 0) ? b_enc2[c] : 0.f;
  #pragma unroll 8
  for (int j = 0; j < 64; ++j) acc = fmaf(ts[j], w_enc2[(hb * 64 + j) * DH + c], acc);
  W[W2PART + hb * DH + c] = acc;
}

// K8: weighted chunk reduce + matvec with w_out. grid (2 o-groups, 16 c-chunks)
__global__ __launch_bounds__(256) void k_out(const float* __restrict__ w_out,
                                             float* __restrict__ W) {
  __shared__ float wv[64];
  int t = threadIdx.x, ob = blockIdx.x, cb = blockIdx.y;
  if (t < 64) {
    int c = cb * 64 + t;
    float v = 0.f;
    #pragma unroll
    for (int p = 0; p < 16; ++p) v += W[W2PART + p * DH + c];
    wv[t] = v;
  }
  __syncthreads();
  int o = ob * 256 + t;
  float acc = 0.f;
  #pragma unroll 8
  for (int j = 0; j < 64; ++j) acc = fmaf(wv[j], w_out[(cb * 64 + j) * DIN + o], acc);
  W[OPART + cb * DIN + o] = acc;
}

// K9: final reduce + bias + tension
__global__ __launch_bounds__(256) void k_final(const float* __restrict__ b_out,
                                               float* __restrict__ W,
                                               float* __restrict__ out) {
  int o = blockIdx.x * 256 + threadIdx.x;
  float acc = b_out[o];
  #pragma unroll
  for (int p = 0; p < 16; ++p) acc += W[OPART + p * DIN + o];
  out[o] = acc;
  if (o == 0) out[DIN] = W[TENS];
}

extern "C" void kernel_launch(void* const* d_in, const int* in_sizes, int n_in,
                              void* d_out, int out_size, void* d_ws, size_t ws_size,
                              hipStream_t stream) {
  (void)in_sizes; (void)n_in; (void)out_size; (void)ws_size;
  const float* x        = (const float*)d_in[0];
  const float* phases   = (const float*)d_in[1];
  const float* omegas   = (const float*)d_in[2];
  const float* coupling = (const float*)d_in[3];
  const float* Kp       = (const float*)d_in[4];
  const float* w_p2h    = (const float*)d_in[5];
  const float* b_p2h    = (const float*)d_in[6];
  const float* w_enc1   = (const float*)d_in[7];
  const float* b_enc1   = (const float*)d_in[8];
  const float* w_enc2   = (const float*)d_in[9];
  const float* b_enc2   = (const float*)d_in[10];
  const float* w_out    = (const float*)d_in[11];
  const float* b_out    = (const float*)d_in[12];
  const int*   step     = (const int*)d_in[13];
  float* W   = (float*)d_ws;
  float* out = (float*)d_out;

  k_prep <<<33, 256, 0, stream>>>(phases, x, W);
  k_rows <<<NC, 256, 0, stream>>>(coupling, phases, omegas, Kp, W);
  k_stats<<<1, 1024, 0, stream>>>(W);
  k_uprep<<<dim3(4, 16), 256, 0, stream>>>(w_p2h, b_p2h, w_enc1, b_enc1, x, W);
  k_ured <<<12, 256, 0, stream>>>(W);
  k_cells<<<128, 256, 0, stream>>>(step, W);
  k_wv   <<<dim3(4, 16), 256, 0, stream>>>(w_enc2, b_enc2, W);
  k_out  <<<dim3(2, 16), 256, 0, stream>>>(w_out, W);
  k_final<<<2, 256, 0, stream>>>(b_out, W, out);
}

// Round 2
// 88.857 us; speedup vs baseline: 1.2785x; 1.2785x over previous
//
#include <hip/hip_runtime.h>
#include <math.h>

// OscillatorEngine on MI355X — round 2.
// N=8192 cells, D_IN=512, D_H=1024, 8 factions of 1024, dc=256, SYNC=.15, DEBATE=.15
//
// Same algebraic restructuring as round 1 (exact in real arithmetic):
//  interactions[i] = (K/N)(sin p_i * Sc_i - cos p_i * Ss_i)   [one streaming pass over C]
//  cell_hiddens rank-2 in per-cell (a_i, b_i)  ->  pre1[i] = a_i u0 + b_i u1 + u2
//  weighted = (sum_i w_i tanh(pre1_i)) @ w_enc2 + b_enc2      [softmax weights sum to 1]
//
// Round-2 deltas: k_rows 2 rows/block + nontemporal loads + 1-barrier reduction;
// k_stats 3-barrier wave-parallel version fused with ured; uprep fused into prep.

#define NC   8192
#define DH   1024
#define DIN  512

using f4 = __attribute__((ext_vector_type(4))) float;

// workspace layout (float offsets)
constexpr int IMG = 0, SBAR = 1, CBAR = 2, MPC = 3, MPS = 4, DEN = 5, TENS = 6;
constexpr int SFO = 8, CFO = 16;                 // faction means [8] each
constexpr int SN0 = 32;                          // sin(old phases) [8192]
constexpr int CN0 = SN0 + NC;                    // cos(old phases)
constexpr int SNN = CN0 + NC;                    // sin(new phases)
constexpr int CNN = SNN + NC;                    // cos(new phases)
constexpr int UPART  = CNN + NC;                 // [16][3][1024]
constexpr int UFIN   = UPART + 16 * 3 * DH;      // [3][1024]
constexpr int TPART  = UFIN + 3 * DH;            // [128][1024]
constexpr int W2PART = TPART + 128 * DH;         // [16][1024]
constexpr int OPART  = W2PART + 16 * DH;         // [16][512]

__device__ __forceinline__ float frcp(float x) { return __builtin_amdgcn_rcpf(x); }
__device__ __forceinline__ float sigm(float x) { return frcp(1.f + __expf(-x)); }
__device__ __forceinline__ float ftanh(float x) { return 1.f - 2.f * frcp(__expf(2.f * x) + 1.f); }

template <int BS>
__device__ __forceinline__ float block_reduce(float v, float* sh) {
  #pragma unroll
  for (int m = 1; m < 64; m <<= 1) v += __shfl_xor(v, m, 64);
  constexpr int NW = BS / 64;
  int lane = threadIdx.x & 63, w = threadIdx.x >> 6;
  if (lane == 0) sh[w] = v;
  __syncthreads();
  if (w == 0) {
    float x = (lane < NW) ? sh[lane] : 0.f;
    #pragma unroll
    for (int m = 1; m < NW; m <<= 1) x += __shfl_xor(x, m, 64);
    if (lane == 0) sh[0] = x;
  }
  __syncthreads();
  float r = sh[0];
  __syncthreads();
  return r;
}

// K1: sincos(old phases) [b<32], ||x|| [b==32], u0/u1/u2 partials [b>=33]
__global__ __launch_bounds__(256) void k_prep_up(const float* __restrict__ phases,
                                                 const float* __restrict__ x,
                                                 const float* __restrict__ w_p2h,
                                                 const float* __restrict__ b_p2h,
                                                 const float* __restrict__ w_enc1,
                                                 const float* __restrict__ b_enc1,
                                                 float* __restrict__ W) {
  __shared__ float sh[4];
  int b = blockIdx.x, t = threadIdx.x;
  if (b < 32) {
    int i = b * 256 + t;
    float s, c;
    sincosf(phases[i], &s, &c);
    W[SN0 + i] = s;
    W[CN0 + i] = c;
  } else if (b == 32) {
    float x0 = x[t], x1 = x[t + 256];
    float v = block_reduce<256>(x0 * x0 + x1 * x1, sh);
    if (t == 0) W[IMG] = sqrtf(v);
  } else {
    int idx = b - 33;       // 0..63
    int hb = idx & 3;       // 4 h-groups of 256
    int dy = idx >> 2;      // 16 d-chunks
    int h = hb * 256 + t;
    float a0 = 0.f, a1 = 0.f, a2 = 0.f;
    for (int d = dy * 64; d < dy * 64 + 64; ++d) {
      float r = w_enc1[d * DH + h];
      a0 = fmaf(w_p2h[d], r, a0);
      a1 = fmaf(w_p2h[DH + d], r, a1);
      a2 = fmaf(b_p2h[d], r, a2);
    }
    for (int k = dy * 32; k < dy * 32 + 32; ++k)
      a2 = fmaf(x[k], w_enc1[(DH + k) * DH + h], a2);
    if (dy == 0) a2 += b_enc1[h];
    float* up = W + UPART + dy * 3 * DH;
    up[h] = a0;
    up[DH + h] = a1;
    up[2 * DH + h] = a2;
  }
}

// K2: the 256 MB streaming pass. 2 rows per block, nontemporal, 1-barrier reduce.
__global__ __launch_bounds__(256) void k_rows(const float* __restrict__ coupling,
                                              const float* __restrict__ phases,
                                              const float* __restrict__ omegas,
                                              const float* __restrict__ Kp,
                                              float* __restrict__ W) {
  __shared__ float sh[4][4];
  int t = threadIdx.x;
  int row0 = blockIdx.x * 2;
  const f4* c0 = (const f4*)(coupling + (size_t)row0 * NC);
  const f4* c1 = (const f4*)(coupling + (size_t)(row0 + 1) * NC);
  const f4* s4 = (const f4*)(W + SN0);
  const f4* c4 = (const f4*)(W + CN0);
  float sc0 = 0.f, ss0 = 0.f, sc1 = 0.f, ss1 = 0.f;
  #pragma unroll 4
  for (int k = 0; k < 8; ++k) {
    int idx = k * 256 + t;
    f4 cc = c4[idx];
    f4 sv = s4[idx];
    f4 v0 = __builtin_nontemporal_load(c0 + idx);
    f4 v1 = __builtin_nontemporal_load(c1 + idx);
    #pragma unroll
    for (int e = 0; e < 4; ++e) {
      float g0 = sigm(v0[e]);
      sc0 = fmaf(g0, cc[e], sc0);
      ss0 = fmaf(g0, sv[e], ss0);
      float g1 = sigm(v1[e]);
      sc1 = fmaf(g1, cc[e], sc1);
      ss1 = fmaf(g1, sv[e], ss1);
    }
  }
  #pragma unroll
  for (int m = 1; m < 64; m <<= 1) {
    sc0 += __shfl_xor(sc0, m, 64);
    ss0 += __shfl_xor(ss0, m, 64);
    sc1 += __shfl_xor(sc1, m, 64);
    ss1 += __shfl_xor(ss1, m, 64);
  }
  int lane = t & 63, w = t >> 6;
  if (lane == 0) { sh[w][0] = sc0; sh[w][1] = ss0; sh[w][2] = sc1; sh[w][3] = ss1; }
  __syncthreads();
  if (t < 2) {
    float sc = sh[0][2 * t] + sh[1][2 * t] + sh[2][2 * t] + sh[3][2 * t];
    float ss = sh[0][2 * t + 1] + sh[1][2 * t + 1] + sh[2][2 * t + 1] + sh[3][2 * t + 1];
    int row = row0 + t;
    float kk = Kp[0];
    float si = W[SN0 + row], ci = W[CN0 + row];
    float inter = (kk / (float)NC) * (si * sc - ci * ss);
    float dtheta = omegas[row] + inter + 0.1f * W[IMG];
    float pn = phases[row] + 0.1f * dtheta;  // mod 2pi dropped: only sin/cos consumed
    float s, c;
    sincosf(pn, &s, &c);
    W[SNN + row] = s;
    W[CNN + row] = c;
  }
}

// K3: block 0 = stats (3 barriers); blocks 1..3 = u-partial reduction.
__global__ __launch_bounds__(1024) void k_stats_ured(float* __restrict__ W) {
  if (blockIdx.x > 0) {
    int j = (blockIdx.x - 1) * 1024 + threadIdx.x;  // 0..3071
    float v = 0.f;
    #pragma unroll
    for (int p = 0; p < 16; ++p) v += W[UPART + p * 3 * DH + j];
    W[UFIN + j] = v;
    return;
  }
  __shared__ float shS[16], shC[16], shD[16], shMP[2];
  int t = threadIdx.x, lane = t & 63, w = t >> 6;
  int f = w >> 1, half = w & 1;
  int base = f * 1024 + half * 512;
  float s = 0.f, c = 0.f;
  #pragma unroll
  for (int k = 0; k < 8; ++k) {
    int i = base + k * 64 + lane;
    s += W[SNN + i];
    c += W[CNN + i];
  }
  #pragma unroll
  for (int m = 1; m < 64; m <<= 1) {
    s += __shfl_xor(s, m, 64);
    c += __shfl_xor(c, m, 64);
  }
  if (lane == 0) { shS[w] = s; shC[w] = c; }
  __syncthreads();
  if (t == 0) {
    float ssum = 0.f, csum = 0.f;
    #pragma unroll
    for (int ff = 0; ff < 8; ++ff) {
      float S = shS[2 * ff] + shS[2 * ff + 1];
      float C = shC[2 * ff] + shC[2 * ff + 1];
      W[SFO + ff] = S * (1.f / 1024.f);
      W[CFO + ff] = C * (1.f / 1024.f);
      ssum += S;
      csum += C;
    }
    float sbar = ssum * (1.f / (float)NC);
    float cbar = csum * (1.f / (float)NC);
    float mp = atan2f(sbar, cbar);
    float mpc = cosf(mp), mps = sinf(mp);
    W[SBAR] = sbar; W[CBAR] = cbar; W[MPC] = mpc; W[MPS] = mps;
    float r = sqrtf(cbar * cbar + sbar * sbar);
    W[TENS] = fabsf(r - 0.5f) * 2.f;
    shMP[0] = mpc; shMP[1] = mps;
  }
  __syncthreads();
  float mpc = shMP[0], mps = shMP[1];
  float d = 0.f;
  #pragma unroll
  for (int k = 0; k < 8; ++k) {
    int i = k * 1024 + t;
    float coh = W[CNN + i] * mpc + W[SNN + i] * mps;
    d += __expf(5.f * coh - 5.f);  // shift by const 5: cancels in normalization
  }
  #pragma unroll
  for (int m = 1; m < 64; m <<= 1) d += __shfl_xor(d, m, 64);
  if (lane == 0) shD[w] = d;
  __syncthreads();
  if (t == 0) {
    float D = 0.f;
    #pragma unroll
    for (int ww = 0; ww < 16; ++ww) D += shD[ww];
    W[DEN] = D;
  }
}

// K4: per-cell rank-2 eval + tanh + softmax-weighted accumulate. 128 blocks x 64 cells.
__global__ __launch_bounds__(256) void k_cells(const int* __restrict__ step,
                                               float* __restrict__ W) {
  int t = threadIdx.x, b = blockIdx.x;
  float u0[4], u1[4], u2[4], acc[4] = {0.f, 0.f, 0.f, 0.f};
  #pragma unroll
  for (int k = 0; k < 4; ++k) {
    int h = t + k * 256;
    u0[k] = W[UFIN + h];
    u1[k] = W[UFIN + DH + h];
    u2[k] = W[UFIN + 2 * DH + h];
  }
  bool debate = step[0] > 5;
  float sbar = W[SBAR], cbar = W[CBAR], mpc = W[MPC], mps = W[MPS];
  float invden = 1.0f / W[DEN];
  int i0 = b * 64;
  int f = i0 >> 10;  // 64-cell chunk never crosses a faction boundary
  float Sf = W[SFO + f], Cf = W[CFO + f];
  bool deb = debate && ((i0 & 1023) < 256);  // dc = FS/4 = 256; uniform per chunk
  for (int j = 0; j < 64; ++j) {
    int i = i0 + j;
    float s = W[SNN + i], c = W[CNN + i];
    float a = fmaf(0.15f, Sf, 0.85f * s);
    float bb = fmaf(0.15f, Cf, 0.85f * c);
    if (deb) {
      a = fmaf(0.15f, sbar, 0.85f * a);
      bb = fmaf(0.15f, cbar, 0.85f * bb);
    }
    float coh = c * mpc + s * mps;
    float wgt = __expf(5.f * coh - 5.f) * invden;
    #pragma unroll
    for (int k = 0; k < 4; ++k) {
      float pre = fmaf(a, u0[k], fmaf(bb, u1[k], u2[k]));
      acc[k] = fmaf(wgt, ftanh(pre), acc[k]);
    }
  }
  #pragma unroll
  for (int k = 0; k < 4; ++k) W[TPART + b * DH + t + k * 256] = acc[k];
}

// K5: t_sum chunk reduce + matvec with w_enc2. grid (4 c-groups, 16 h-chunks)
__global__ __launch_bounds__(256) void k_wv(const float* __restrict__ w_enc2,
                                            const float* __restrict__ b_enc2,
                                            float* __restrict__ W) {
  __shared__ float ts[64];
  int t = threadIdx.x, cb = blockIdx.x, hb = blockIdx.y;
  if (t < 64) {
    int h = hb * 64 + t;
    float v = 0.f;
    for (int p = 0; p < 128; ++p) v += W[TPART + p * DH + h];
    ts[t] = v;
  }
  __syncthreads();
  int c = cb * 256 + t;
  float acc = (hb == 0) ? b_enc2[c] : 0.f;
  #pragma unroll 8
  for (int j = 0; j < 64; ++j) acc = fmaf(ts[j], w_enc2[(hb * 64 + j) * DH + c], acc);
  W[W2PART + hb * DH + c] = acc;
}

// K6: weighted chunk reduce + matvec with w_out. grid (2 o-groups, 16 c-chunks)
__global__ __launch_bounds__(256) void k_out(const float* __restrict__ w_out,
                                             float* __restrict__ W) {
  __shared__ float wv[64];
  int t = threadIdx.x, ob = blockIdx.x, cb = blockIdx.y;
  if (t < 64) {
    int c = cb * 64 + t;
    float v = 0.f;
    #pragma unroll
    for (int p = 0; p < 16; ++p) v += W[W2PART + p * DH + c];
    wv[t] = v;
  }
  __syncthreads();
  int o = ob * 256 + t;
  float acc = 0.f;
  #pragma unroll 8
  for (int j = 0; j < 64; ++j) acc = fmaf(wv[j], w_out[(cb * 64 + j) * DIN + o], acc);
  W[OPART + cb * DIN + o] = acc;
}

// K7: final reduce + bias + tension
__global__ __launch_bounds__(256) void k_final(const float* __restrict__ b_out,
                                               float* __restrict__ W,
                                               float* __restrict__ out) {
  int o = blockIdx.x * 256 + threadIdx.x;
  float acc = b_out[o];
  #pragma unroll
  for (int p = 0; p < 16; ++p) acc += W[OPART + p * DIN + o];
  out[o] = acc;
  if (o == 0) out[DIN] = W[TENS];
}

extern "C" void kernel_launch(void* const* d_in, const int* in_sizes, int n_in,
                              void* d_out, int out_size, void* d_ws, size_t ws_size,
                              hipStream_t stream) {
  (void)in_sizes; (void)n_in; (void)out_size; (void)ws_size;
  const float* x        = (const float*)d_in[0];
  const float* phases   = (const float*)d_in[1];
  const float* omegas   = (const float*)d_in[2];
  const float* coupling = (const float*)d_in[3];
  const float* Kp       = (const float*)d_in[4];
  const float* w_p2h    = (const float*)d_in[5];
  const float* b_p2h    = (const float*)d_in[6];
  const float* w_enc1   = (const float*)d_in[7];
  const float* b_enc1   = (const float*)d_in[8];
  const float* w_enc2   = (const float*)d_in[9];
  const float* b_enc2   = (const float*)d_in[10];
  const float* w_out    = (const float*)d_in[11];
  const float* b_out    = (const float*)d_in[12];
  const int*   step     = (const int*)d_in[13];
  float* W   = (float*)d_ws;
  float* out = (float*)d_out;

  k_prep_up   <<<97, 256, 0, stream>>>(phases, x, w_p2h, b_p2h, w_enc1, b_enc1, W);
  k_rows      <<<NC / 2, 256, 0, stream>>>(coupling, phases, omegas, Kp, W);
  k_stats_ured<<<4, 1024, 0, stream>>>(W);
  k_cells     <<<128, 256, 0, stream>>>(step, W);
  k_wv        <<<dim3(4, 16), 256, 0, stream>>>(w_enc2, b_enc2, W);
  k_out       <<<dim3(2, 16), 256, 0, stream>>>(w_out, W);
  k_final     <<<2, 256, 0, stream>>>(b_out, W, out);
}